// Round 1
// baseline (370.727 us; speedup 1.0000x reference)
//
#include <hip/hip_runtime.h>

typedef short bf16x8 __attribute__((ext_vector_type(8)));
typedef float f32x4 __attribute__((ext_vector_type(4)));
typedef float float4v __attribute__((ext_vector_type(4)));
typedef short short4v __attribute__((ext_vector_type(4)));

#define B_ 4
#define S_ 2048
#define E_ 1024
#define H_ 16
#define D_ 64
#define M_ (B_*S_)      // 8192
#define N1_ (3*E_)      // 3072

// fp32 -> bf16 round-to-nearest-even (values are finite; no NaN handling needed)
__device__ inline short f2bs(float f) {
    unsigned u = __builtin_bit_cast(unsigned, f);
    unsigned r = u + 0x7fffu + ((u >> 16) & 1u);
    return (short)(r >> 16);
}

__device__ inline const __attribute__((address_space(1))) void* gas(const void* p) {
    return (const __attribute__((address_space(1))) void*)p;
}
__device__ inline __attribute__((address_space(3))) void* las(void* p) {
    return (__attribute__((address_space(3))) void*)p;
}

// ---------------- elementwise fp32 -> bf16 ----------------
__global__ void convert_f32_bf16(const float* __restrict__ in, short* __restrict__ out, int n) {
    int tid = blockIdx.x * blockDim.x + threadIdx.x;
    int stride = gridDim.x * blockDim.x;
    for (int i = tid * 4; i < n; i += stride * 4) {
        float4v v = *(const float4v*)&in[i];
        short4v o;
        o[0] = f2bs(v[0]); o[1] = f2bs(v[1]); o[2] = f2bs(v[2]); o[3] = f2bs(v[3]);
        *(short4v*)&out[i] = o;
    }
}

// ---------------- tiled transpose + convert: out[c][r] = bf16(in[r][c]) ----------------
__global__ void transpose_convert(const float* __restrict__ in, short* __restrict__ out,
                                  int rows, int cols) {
    __shared__ float t[32][33];
    int bx = blockIdx.x * 32;  // col base
    int by = blockIdx.y * 32;  // row base
    int tx = threadIdx.x, ty = threadIdx.y;  // (32, 8)
#pragma unroll
    for (int i = 0; i < 4; ++i)
        t[ty + i * 8][tx] = in[(size_t)(by + ty + i * 8) * cols + bx + tx];
    __syncthreads();
#pragma unroll
    for (int i = 0; i < 4; ++i)
        out[(size_t)(bx + ty + i * 8) * rows + by + tx] = f2bs(t[tx][ty + i * 8]);
}

// ---------------- bf16 GEMM, 128x128 tile, BK=32, global_load_lds staging ----------------
// C = A[M][K] * Bt[N][K]^T.  EPI=0: scatter to Q/K/V bf16. EPI=1: fp32 C + bias.
template <int EPI>
__global__ __launch_bounds__(256, 2) void gemm_bt(
    const short* __restrict__ A, const short* __restrict__ Bt,
    const float* __restrict__ bias, float* __restrict__ Cf,
    short* __restrict__ Qb, short* __restrict__ Kb, short* __restrict__ Vt,
    int Kdim, int Ndim) {
    __shared__ __attribute__((aligned(16))) short As[128 * 32];
    __shared__ __attribute__((aligned(16))) short Bs[128 * 32];
    const int lane = threadIdx.x & 63;
    const int wv = threadIdx.x >> 6;
    const int row0 = blockIdx.y * 128;
    const int col0 = blockIdx.x * 128;
    const int wr = (wv >> 1) * 64;
    const int wc = (wv & 1) * 64;
    const int li = lane & 15;
    const int g = lane >> 4;
    const int lr = lane >> 2;        // 0..15 row-within-chunk
    const int lk = (lane & 3) * 8;   // k element offset

    f32x4 acc[4][4];
#pragma unroll
    for (int m = 0; m < 4; ++m)
#pragma unroll
        for (int n = 0; n < 4; ++n) acc[m][n] = (f32x4){0.f, 0.f, 0.f, 0.f};

    for (int k0 = 0; k0 < Kdim; k0 += 32) {
#pragma unroll
        for (int i = 0; i < 2; ++i) {
            int cc = wv * 2 + i;
            const short* ga = A + (size_t)(row0 + cc * 16 + lr) * Kdim + k0 + lk;
            __builtin_amdgcn_global_load_lds(gas(ga), las(&As[cc * 512]), 16, 0, 0);
            const short* gb = Bt + (size_t)(col0 + cc * 16 + lr) * Kdim + k0 + lk;
            __builtin_amdgcn_global_load_lds(gas(gb), las(&Bs[cc * 512]), 16, 0, 0);
        }
        __syncthreads();
        bf16x8 af[4], bfr[4];
#pragma unroll
        for (int m = 0; m < 4; ++m) af[m] = *(const bf16x8*)&As[(wr + 16 * m + li) * 32 + g * 8];
#pragma unroll
        for (int n = 0; n < 4; ++n) bfr[n] = *(const bf16x8*)&Bs[(wc + 16 * n + li) * 32 + g * 8];
#pragma unroll
        for (int m = 0; m < 4; ++m)
#pragma unroll
            for (int n = 0; n < 4; ++n)
                acc[m][n] = __builtin_amdgcn_mfma_f32_16x16x32_bf16(af[m], bfr[n], acc[m][n], 0, 0, 0);
        __syncthreads();
    }

    // epilogue: C layout col = lane&15, row = (lane>>4)*4 + j  [m89/m91 verified]
    if constexpr (EPI == 1) {
#pragma unroll
        for (int n = 0; n < 4; ++n) {
            int ncol = col0 + wc + 16 * n + li;
            float bv = bias[ncol];
#pragma unroll
            for (int m = 0; m < 4; ++m) {
                int rbase = row0 + wr + 16 * m + 4 * g;
#pragma unroll
                for (int j = 0; j < 4; ++j)
                    Cf[(size_t)(rbase + j) * Ndim + ncol] = acc[m][n][j] + bv;
            }
        }
    } else {
#pragma unroll
        for (int n = 0; n < 4; ++n) {
            int ncol = col0 + wc + 16 * n + li;
            float bv = bias[ncol];
            int part = ncol >> 10;
            int rem = ncol & 1023;
            int h = rem >> 6;
            int d = rem & 63;
#pragma unroll
            for (int m = 0; m < 4; ++m) {
                int rbase = row0 + wr + 16 * m + 4 * g;
#pragma unroll
                for (int j = 0; j < 4; ++j) {
                    int row = rbase + j;
                    int bb = row >> 11;
                    int ss = row & 2047;
                    short o = f2bs(acc[m][n][j] + bv);
                    if (part == 0)
                        Qb[((size_t)(bb * H_ + h) * S_ + ss) * D_ + d] = o;
                    else if (part == 1)
                        Kb[((size_t)(bb * H_ + h) * S_ + ss) * D_ + d] = o;
                    else
                        Vt[((size_t)(bb * H_ + h) * D_ + d) * S_ + ss] = o;
                }
            }
        }
    }
}

// ---------------- causal flash attention ----------------
// grid (S/128, B*H), block 256. Wave wv owns q rows [qtile*128 + wv*32, +32).
// Q,K: [B,H,S,D] bf16; V: [B,H,D,S] bf16 (pre-transposed). Out: [B,S,E] bf16.
__global__ __launch_bounds__(256, 2) void attn_kernel(
    const short* __restrict__ Qb, const short* __restrict__ Kb,
    const short* __restrict__ Vt, short* __restrict__ Ob) {
    __shared__ __attribute__((aligned(16))) short Plds[4][1024];  // per-wave 16x64 P tile
    const int lane = threadIdx.x & 63;
    const int wv = threadIdx.x >> 6;
    const int li = lane & 15;
    const int g = lane >> 4;
    const int bh = blockIdx.y;
    const int bb = bh >> 4;
    const int hh = bh & 15;
    const short* Qh = Qb + (size_t)bh * (S_ * D_);
    const short* Kh = Kb + (size_t)bh * (S_ * D_);
    const short* Vh = Vt + (size_t)bh * (D_ * S_);
    const int qbase = blockIdx.x * 128 + wv * 32;

    bf16x8 qa[2][2];
#pragma unroll
    for (int qf = 0; qf < 2; ++qf)
#pragma unroll
        for (int kt = 0; kt < 2; ++kt)
            qa[qf][kt] = *(const bf16x8*)&Qh[(size_t)(qbase + qf * 16 + li) * D_ + kt * 32 + g * 8];

    f32x4 acc[2][4];
    float mrow[2][4], lrow[2][4];
#pragma unroll
    for (int qf = 0; qf < 2; ++qf) {
#pragma unroll
        for (int dc = 0; dc < 4; ++dc) acc[qf][dc] = (f32x4){0.f, 0.f, 0.f, 0.f};
#pragma unroll
        for (int j = 0; j < 4; ++j) { mrow[qf][j] = -1e30f; lrow[qf][j] = 0.f; }
    }

    const int kend = qbase + 32;  // causal: keys < kend (rest masked anyway)
    for (int kt0 = 0; kt0 < kend; kt0 += 64) {
        bf16x8 kf[4][2], vf[4][2];
#pragma unroll
        for (int kc = 0; kc < 4; ++kc)
#pragma unroll
            for (int kt = 0; kt < 2; ++kt)
                kf[kc][kt] = *(const bf16x8*)&Kh[(size_t)(kt0 + kc * 16 + li) * D_ + kt * 32 + g * 8];
#pragma unroll
        for (int dc = 0; dc < 4; ++dc)
#pragma unroll
            for (int kt2 = 0; kt2 < 2; ++kt2)
                vf[dc][kt2] = *(const bf16x8*)&Vh[(size_t)(dc * 16 + li) * S_ + kt0 + kt2 * 32 + g * 8];

#pragma unroll
        for (int qf = 0; qf < 2; ++qf) {
            const int q0 = qbase + qf * 16;
            f32x4 sc[4];
#pragma unroll
            for (int kc = 0; kc < 4; ++kc) {
                f32x4 z = (f32x4){0.f, 0.f, 0.f, 0.f};
                z = __builtin_amdgcn_mfma_f32_16x16x32_bf16(qa[qf][0], kf[kc][0], z, 0, 0, 0);
                z = __builtin_amdgcn_mfma_f32_16x16x32_bf16(qa[qf][1], kf[kc][1], z, 0, 0, 0);
                sc[kc] = z;
            }
            // scale + causal mask + row max (S layout: col=key=lane&15, row=4g+j)
            float tmax[4] = {-1e30f, -1e30f, -1e30f, -1e30f};
#pragma unroll
            for (int kc = 0; kc < 4; ++kc) {
                int key = kt0 + kc * 16 + li;
#pragma unroll
                for (int j = 0; j < 4; ++j) {
                    int qr = q0 + 4 * g + j;
                    float v = sc[kc][j] * 0.125f;
                    v = (key > qr) ? -1e30f : v;
                    sc[kc][j] = v;
                    tmax[j] = fmaxf(tmax[j], v);
                }
            }
#pragma unroll
            for (int msk = 1; msk < 16; msk <<= 1)
#pragma unroll
                for (int j = 0; j < 4; ++j)
                    tmax[j] = fmaxf(tmax[j], __shfl_xor(tmax[j], msk, 64));
            float mn[4], sf[4], rs[4];
#pragma unroll
            for (int j = 0; j < 4; ++j) {
                mn[j] = fmaxf(mrow[qf][j], tmax[j]);
                sf[j] = __expf(mrow[qf][j] - mn[j]);
                mrow[qf][j] = mn[j];
                lrow[qf][j] *= sf[j];
                rs[j] = 0.f;
            }
#pragma unroll
            for (int dc = 0; dc < 4; ++dc)
#pragma unroll
                for (int j = 0; j < 4; ++j) acc[qf][dc][j] *= sf[j];
#pragma unroll
            for (int kc = 0; kc < 4; ++kc)
#pragma unroll
                for (int j = 0; j < 4; ++j) {
                    float p = __expf(sc[kc][j] - mn[j]);
                    rs[j] += p;
                    Plds[wv][(4 * g + j) * 64 + kc * 16 + li] = f2bs(p);
                }
#pragma unroll
            for (int msk = 1; msk < 16; msk <<= 1)
#pragma unroll
                for (int j = 0; j < 4; ++j) rs[j] += __shfl_xor(rs[j], msk, 64);
#pragma unroll
            for (int j = 0; j < 4; ++j) lrow[qf][j] += rs[j];

            // wave-internal LDS transpose: wait for all lanes' ds_writes, then read A-frags
            asm volatile("s_waitcnt lgkmcnt(0)" ::: "memory");
            __builtin_amdgcn_sched_barrier(0);
            bf16x8 pa[2];
#pragma unroll
            for (int kt2 = 0; kt2 < 2; ++kt2)
                pa[kt2] = *(const bf16x8*)&Plds[wv][li * 64 + kt2 * 32 + g * 8];
#pragma unroll
            for (int dc = 0; dc < 4; ++dc) {
                acc[qf][dc] = __builtin_amdgcn_mfma_f32_16x16x32_bf16(pa[0], vf[dc][0], acc[qf][dc], 0, 0, 0);
                acc[qf][dc] = __builtin_amdgcn_mfma_f32_16x16x32_bf16(pa[1], vf[dc][1], acc[qf][dc], 0, 0, 0);
            }
        }
    }

#pragma unroll
    for (int qf = 0; qf < 2; ++qf)
#pragma unroll
        for (int dc = 0; dc < 4; ++dc)
#pragma unroll
            for (int j = 0; j < 4; ++j) {
                int srow = qbase + qf * 16 + 4 * g + j;
                float val = acc[qf][dc][j] / lrow[qf][j];
                Ob[((size_t)(bb * S_ + srow)) * E_ + hh * 64 + dc * 16 + li] = f2bs(val);
            }
}

extern "C" void kernel_launch(void* const* d_in, const int* in_sizes, int n_in,
                              void* d_out, int out_size, void* d_ws, size_t ws_size,
                              hipStream_t stream) {
    const float* x      = (const float*)d_in[0];
    const float* w_attn = (const float*)d_in[1];
    const float* b_attn = (const float*)d_in[2];
    const float* w_out  = (const float*)d_in[3];
    const float* b_out  = (const float*)d_in[4];
    float* out = (float*)d_out;

    char* ws = (char*)d_ws;
    short* Xbf  = (short*)(ws);                       // 16 MB (reused as attn output)
    short* Wat  = (short*)(ws + (16ull << 20));       // 6 MB  [3072][1024]
    short* Wot  = (short*)(ws + (22ull << 20));       // 2 MB  [1024][1024]
    short* Qb   = (short*)(ws + (24ull << 20));       // 16 MB [B,H,S,D]
    short* Kb   = (short*)(ws + (40ull << 20));       // 16 MB [B,H,S,D]
    short* Vt   = (short*)(ws + (56ull << 20));       // 16 MB [B,H,D,S]
    short* Obuf = Xbf;                                // alias: x_bf16 dead after QKV GEMM

    convert_f32_bf16<<<2048, 256, 0, stream>>>(x, Xbf, M_ * E_);
    transpose_convert<<<dim3(N1_ / 32, E_ / 32), dim3(32, 8), 0, stream>>>(w_attn, Wat, E_, N1_);
    transpose_convert<<<dim3(E_ / 32, E_ / 32), dim3(32, 8), 0, stream>>>(w_out, Wot, E_, E_);

    gemm_bt<0><<<dim3(N1_ / 128, M_ / 128), 256, 0, stream>>>(
        Xbf, Wat, b_attn, nullptr, Qb, Kb, Vt, E_, N1_);

    attn_kernel<<<dim3(S_ / 128, B_ * H_), 256, 0, stream>>>(Qb, Kb, Vt, Obuf);

    gemm_bt<1><<<dim3(E_ / 128, M_ / 128), 256, 0, stream>>>(
        Obuf, Wot, b_out, out, nullptr, nullptr, nullptr, E_, E_);
}

// Round 2
// 227.513 us; speedup vs baseline: 1.6295x; 1.6295x over previous
//
#include <hip/hip_runtime.h>

typedef short bf16x8 __attribute__((ext_vector_type(8)));
typedef float f32x4 __attribute__((ext_vector_type(4)));
typedef float float4v __attribute__((ext_vector_type(4)));
typedef short short4v __attribute__((ext_vector_type(4)));

#define B_ 4
#define S_ 2048
#define E_ 1024
#define H_ 16
#define D_ 64
#define M_ (B_*S_)      // 8192
#define N1_ (3*E_)      // 3072

// fp32 -> bf16 round-to-nearest-even
__device__ inline short f2bs(float f) {
    unsigned u = __builtin_bit_cast(unsigned, f);
    unsigned r = u + 0x7fffu + ((u >> 16) & 1u);
    return (short)(r >> 16);
}
__device__ inline float exp2a(float x) {  // v_exp_f32: 2^x
    float r; asm("v_exp_f32 %0, %1" : "=v"(r) : "v"(x)); return r;
}
__device__ inline unsigned cvtpk(float a, float b) {  // lo=bf16(a), hi=bf16(b)
    unsigned r; asm("v_cvt_pk_bf16_f32 %0, %1, %2" : "=v"(r) : "v"(a), "v"(b)); return r;
}

__device__ inline const __attribute__((address_space(1))) void* gas(const void* p) {
    return (const __attribute__((address_space(1))) void*)p;
}
__device__ inline __attribute__((address_space(3))) void* las(void* p) {
    return (__attribute__((address_space(3))) void*)p;
}

// ---------------- elementwise fp32 -> bf16 ----------------
__global__ void convert_f32_bf16(const float* __restrict__ in, short* __restrict__ out, int n) {
    int tid = blockIdx.x * blockDim.x + threadIdx.x;
    int stride = gridDim.x * blockDim.x;
    for (int i = tid * 4; i < n; i += stride * 4) {
        float4v v = *(const float4v*)&in[i];
        short4v o;
        o[0] = f2bs(v[0]); o[1] = f2bs(v[1]); o[2] = f2bs(v[2]); o[3] = f2bs(v[3]);
        *(short4v*)&out[i] = o;
    }
}

// ---------------- tiled transpose + convert: out[c][r] = bf16(in[r][c]) ----------------
__global__ void transpose_convert(const float* __restrict__ in, short* __restrict__ out,
                                  int rows, int cols) {
    __shared__ float t[32][33];
    int bx = blockIdx.x * 32;
    int by = blockIdx.y * 32;
    int tx = threadIdx.x, ty = threadIdx.y;  // (32, 8)
#pragma unroll
    for (int i = 0; i < 4; ++i)
        t[ty + i * 8][tx] = in[(size_t)(by + ty + i * 8) * cols + bx + tx];
    __syncthreads();
#pragma unroll
    for (int i = 0; i < 4; ++i)
        out[(size_t)(bx + ty + i * 8) * rows + by + tx] = f2bs(t[tx][ty + i * 8]);
}

// ---------------- bf16 GEMM, 128x128 tile, BK=32, global_load_lds staging ----------------
template <int EPI>
__global__ __launch_bounds__(256, 2) void gemm_bt(
    const short* __restrict__ A, const short* __restrict__ Bt,
    const float* __restrict__ bias, float* __restrict__ Cf,
    short* __restrict__ Qb, short* __restrict__ Kb, short* __restrict__ Vt,
    int Kdim, int Ndim) {
    __shared__ __attribute__((aligned(16))) short As[128 * 32];
    __shared__ __attribute__((aligned(16))) short Bs[128 * 32];
    const int lane = threadIdx.x & 63;
    const int wv = threadIdx.x >> 6;
    const int row0 = blockIdx.y * 128;
    const int col0 = blockIdx.x * 128;
    const int wr = (wv >> 1) * 64;
    const int wc = (wv & 1) * 64;
    const int li = lane & 15;
    const int g = lane >> 4;
    const int lr = lane >> 2;
    const int lk = (lane & 3) * 8;

    f32x4 acc[4][4];
#pragma unroll
    for (int m = 0; m < 4; ++m)
#pragma unroll
        for (int n = 0; n < 4; ++n) acc[m][n] = (f32x4){0.f, 0.f, 0.f, 0.f};

    for (int k0 = 0; k0 < Kdim; k0 += 32) {
#pragma unroll
        for (int i = 0; i < 2; ++i) {
            int cc = wv * 2 + i;
            const short* ga = A + (size_t)(row0 + cc * 16 + lr) * Kdim + k0 + lk;
            __builtin_amdgcn_global_load_lds(gas(ga), las(&As[cc * 512]), 16, 0, 0);
            const short* gb = Bt + (size_t)(col0 + cc * 16 + lr) * Kdim + k0 + lk;
            __builtin_amdgcn_global_load_lds(gas(gb), las(&Bs[cc * 512]), 16, 0, 0);
        }
        __syncthreads();
        bf16x8 af[4], bfr[4];
#pragma unroll
        for (int m = 0; m < 4; ++m) af[m] = *(const bf16x8*)&As[(wr + 16 * m + li) * 32 + g * 8];
#pragma unroll
        for (int n = 0; n < 4; ++n) bfr[n] = *(const bf16x8*)&Bs[(wc + 16 * n + li) * 32 + g * 8];
#pragma unroll
        for (int m = 0; m < 4; ++m)
#pragma unroll
            for (int n = 0; n < 4; ++n)
                acc[m][n] = __builtin_amdgcn_mfma_f32_16x16x32_bf16(af[m], bfr[n], acc[m][n], 0, 0, 0);
        __syncthreads();
    }

    if constexpr (EPI == 1) {
#pragma unroll
        for (int n = 0; n < 4; ++n) {
            int ncol = col0 + wc + 16 * n + li;
            float bv = bias[ncol];
#pragma unroll
            for (int m = 0; m < 4; ++m) {
                int rbase = row0 + wr + 16 * m + 4 * g;
#pragma unroll
                for (int j = 0; j < 4; ++j)
                    Cf[(size_t)(rbase + j) * Ndim + ncol] = acc[m][n][j] + bv;
            }
        }
    } else {
#pragma unroll
        for (int n = 0; n < 4; ++n) {
            int ncol = col0 + wc + 16 * n + li;
            float bv = bias[ncol];
            int part = ncol >> 10;
            int rem = ncol & 1023;
            int h = rem >> 6;
            int d = rem & 63;
#pragma unroll
            for (int m = 0; m < 4; ++m) {
                int rbase = row0 + wr + 16 * m + 4 * g;
#pragma unroll
                for (int j = 0; j < 4; ++j) {
                    int row = rbase + j;
                    int bb = row >> 11;
                    int ss = row & 2047;
                    short o = f2bs(acc[m][n][j] + bv);
                    if (part == 0)
                        Qb[((size_t)(bb * H_ + h) * S_ + ss) * D_ + d] = o;
                    else if (part == 1)
                        Kb[((size_t)(bb * H_ + h) * S_ + ss) * D_ + d] = o;
                    else
                        Vt[((size_t)(bb * H_ + h) * D_ + d) * S_ + ss] = o;
                }
            }
        }
    }
}

// ---------------- causal flash attention v2 ----------------
// 512 threads = 8 waves x 16 q-rows = 128-row q-tile. Tiles paired {p, 15-p} for
// uniform work. K/V (64 keys x 64 d) block-staged in LDS via global_load_lds with
// inverse-swizzled global source; reads use matching XOR swizzle (T2).
// Softmax: exp2-folded scale, MFMA ones-column row-sum, cvt_pk bf16 P pack,
// exact skip-rescale, boundary-tile-only masking.
__global__ __launch_bounds__(512, 4) void attn_kernel(
    const short* __restrict__ Qb, const short* __restrict__ Kb,
    const short* __restrict__ Vt, short* __restrict__ Ob) {
    __shared__ __attribute__((aligned(16))) short Kl[4096];       // 8 KB
    __shared__ __attribute__((aligned(16))) short Vl[4096];       // 8 KB
    __shared__ __attribute__((aligned(16))) short Plds[8][1024];  // 16 KB
    const int lane = threadIdx.x & 63;
    const int wv = threadIdx.x >> 6;
    const int li = lane & 15;
    const int g = lane >> 4;
    // XCD grouping: blocks with dispatch_id % 8 == X handle heads [X*8, X*8+8)
    const int d0 = blockIdx.x + blockIdx.y * 8;  // 0..511
    const int X = d0 & 7, kk = d0 >> 3;
    const int bh = X * 8 + (kk >> 3);
    const int pp = kk & 7;
    const int bb = bh >> 4, hh = bh & 15;
    const short* Qh = Qb + (size_t)bh * (S_ * D_);
    const short* Kh = Kb + (size_t)bh * (S_ * D_);
    const short* Vh = Vt + (size_t)bh * (D_ * S_);
    const float CEXP = 0.18033688011112042f;  // (1/8)*log2(e)
    bf16x8 ONES;
#pragma unroll
    for (int i = 0; i < 8; ++i) ONES[i] = (short)0x3F80;

    // staging lane geometry: lane l fills LDS bytes [wv*1024 + l*16, +16)
    const int r8 = lane >> 3;                     // row within wave's 8 rows
    const int c16 = ((lane & 7) ^ r8) << 4;       // swizzled byte-in-row (inverse swz source)
    const int strow = wv * 8 + r8;                // 0..63
    char* Pb = (char*)&Plds[wv][0];
    const int lsw = (li & 7) << 4;                // read-side XOR

    for (int t = 0; t < 2; ++t) {
        const int qt = t ? (15 - pp) : pp;
        const int q0 = qt * 128 + wv * 16;
        bf16x8 qa[2];
#pragma unroll
        for (int c = 0; c < 2; ++c)
            qa[c] = *(const bf16x8*)&Qh[(size_t)(q0 + li) * D_ + c * 32 + g * 8];
        f32x4 acc[4];
        f32x4 lsum = (f32x4){0.f, 0.f, 0.f, 0.f};
#pragma unroll
        for (int dc = 0; dc < 4; ++dc) acc[dc] = (f32x4){0.f, 0.f, 0.f, 0.f};
        float mrow[4], mrowC[4];
#pragma unroll
        for (int j = 0; j < 4; ++j) { mrow[j] = -3e38f; mrowC[j] = 0.f; }

        const int nw = (q0 + 79) >> 6;         // k-tiles this wave computes
        const int nt = (qt * 128 + 191) >> 6;  // k-tiles staged by block (= max over waves)

        for (int it = 0; it < nt; ++it) {
            const int kt0 = it * 64;
            // cooperative stage: K tile + V tile, 16B/lane, linear LDS dest
            {
                const char* gk = (const char*)Kh + (size_t)(kt0 + strow) * 128 + c16;
                __builtin_amdgcn_global_load_lds(gas(gk), las((char*)Kl + wv * 1024), 16, 0, 0);
                const char* gv = (const char*)Vh + (size_t)strow * (S_ * 2) + (size_t)kt0 * 2 + c16;
                __builtin_amdgcn_global_load_lds(gas(gv), las((char*)Vl + wv * 1024), 16, 0, 0);
            }
            __syncthreads();
            if (it < nw) {
                const bool bmask = (it == nw - 1);
                bf16x8 kf[4][2];
#pragma unroll
                for (int kc = 0; kc < 4; ++kc)
#pragma unroll
                    for (int c = 0; c < 2; ++c)
                        kf[kc][c] = *(const bf16x8*)((const char*)Kl + (kc * 16 + li) * 128 +
                                                     ((c * 64 + g * 16) ^ lsw));
                f32x4 sc4[4];
#pragma unroll
                for (int kc = 0; kc < 4; ++kc) {
                    f32x4 z = (f32x4){0.f, 0.f, 0.f, 0.f};
                    z = __builtin_amdgcn_mfma_f32_16x16x32_bf16(qa[0], kf[kc][0], z, 0, 0, 0);
                    z = __builtin_amdgcn_mfma_f32_16x16x32_bf16(qa[1], kf[kc][1], z, 0, 0, 0);
                    sc4[kc] = z;
                }
                if (bmask) {
#pragma unroll
                    for (int kc = 0; kc < 4; ++kc) {
                        int key = kt0 + kc * 16 + li;
#pragma unroll
                        for (int j = 0; j < 4; ++j) {
                            int qr = q0 + 4 * g + j;
                            sc4[kc][j] = (key > qr) ? -3e38f : sc4[kc][j];
                        }
                    }
                }
                float tmax[4];
#pragma unroll
                for (int j = 0; j < 4; ++j)
                    tmax[j] = fmaxf(fmaxf(sc4[0][j], sc4[1][j]), fmaxf(sc4[2][j], sc4[3][j]));
#pragma unroll
                for (int msk = 1; msk < 16; msk <<= 1)
#pragma unroll
                    for (int j = 0; j < 4; ++j)
                        tmax[j] = fmaxf(tmax[j], __shfl_xor(tmax[j], msk, 64));
                bool need = (tmax[0] > mrow[0]) | (tmax[1] > mrow[1]) |
                            (tmax[2] > mrow[2]) | (tmax[3] > mrow[3]);
                if (__ballot((int)need) != 0ull) {
#pragma unroll
                    for (int j = 0; j < 4; ++j) {
                        float mn = fmaxf(mrow[j], tmax[j]);
                        float sf = exp2a((mrow[j] - mn) * CEXP);
                        mrow[j] = mn;
                        mrowC[j] = mn * CEXP;
                        lsum[j] *= sf;
#pragma unroll
                        for (int dc = 0; dc < 4; ++dc) acc[dc][j] *= sf;
                    }
                }
                // P = exp2(s*C - m*C) -> bf16 pairs -> swizzled LDS
#pragma unroll
                for (int j = 0; j < 4; ++j) {
                    const int rowb = (4 * g + j) * 128;
                    const int rx = ((4 * g + j) & 7) << 4;
#pragma unroll
                    for (int kp = 0; kp < 2; ++kp) {
                        float p0 = exp2a(fmaf(sc4[2 * kp][j], CEXP, -mrowC[j]));
                        float p1 = exp2a(fmaf(sc4[2 * kp + 1][j], CEXP, -mrowC[j]));
                        unsigned u = cvtpk(p0, p1);
                        *(short*)(Pb + rowb + ((kp * 64 + li * 2) ^ rx)) = (short)u;
                        *(short*)(Pb + rowb + ((kp * 64 + 32 + li * 2) ^ rx)) = (short)(u >> 16);
                    }
                }
                bf16x8 vf[4][2];
#pragma unroll
                for (int dc = 0; dc < 4; ++dc)
#pragma unroll
                    for (int c = 0; c < 2; ++c)
                        vf[dc][c] = *(const bf16x8*)((const char*)Vl + (dc * 16 + li) * 128 +
                                                     ((c * 64 + g * 16) ^ lsw));
                asm volatile("s_waitcnt lgkmcnt(0)" ::: "memory");
                __builtin_amdgcn_sched_barrier(0);
                bf16x8 pa[2];
#pragma unroll
                for (int c = 0; c < 2; ++c)
                    pa[c] = *(const bf16x8*)(Pb + li * 128 + ((c * 64 + g * 16) ^ lsw));
#pragma unroll
                for (int dc = 0; dc < 4; ++dc) {
                    acc[dc] = __builtin_amdgcn_mfma_f32_16x16x32_bf16(pa[0], vf[dc][0], acc[dc], 0, 0, 0);
                    acc[dc] = __builtin_amdgcn_mfma_f32_16x16x32_bf16(pa[1], vf[dc][1], acc[dc], 0, 0, 0);
                }
                lsum = __builtin_amdgcn_mfma_f32_16x16x32_bf16(pa[0], ONES, lsum, 0, 0, 0);
                lsum = __builtin_amdgcn_mfma_f32_16x16x32_bf16(pa[1], ONES, lsum, 0, 0, 0);
            }
            __syncthreads();
        }
        float rl[4];
#pragma unroll
        for (int j = 0; j < 4; ++j) rl[j] = __builtin_amdgcn_rcpf(lsum[j]);
#pragma unroll
        for (int dc = 0; dc < 4; ++dc)
#pragma unroll
            for (int j = 0; j < 4; ++j) {
                int sr = q0 + 4 * g + j;
                Ob[((size_t)(bb * S_ + sr)) * E_ + hh * 64 + dc * 16 + li] = f2bs(acc[dc][j] * rl[j]);
            }
    }
}

extern "C" void kernel_launch(void* const* d_in, const int* in_sizes, int n_in,
                              void* d_out, int out_size, void* d_ws, size_t ws_size,
                              hipStream_t stream) {
    const float* x      = (const float*)d_in[0];
    const float* w_attn = (const float*)d_in[1];
    const float* b_attn = (const float*)d_in[2];
    const float* w_out  = (const float*)d_in[3];
    const float* b_out  = (const float*)d_in[4];
    float* out = (float*)d_out;

    char* ws = (char*)d_ws;
    short* Xbf  = (short*)(ws);                       // 16 MB (reused as attn output)
    short* Wat  = (short*)(ws + (16ull << 20));       // 6 MB  [3072][1024]
    short* Wot  = (short*)(ws + (22ull << 20));       // 2 MB  [1024][1024]
    short* Qb   = (short*)(ws + (24ull << 20));       // 16 MB [B,H,S,D]
    short* Kb   = (short*)(ws + (40ull << 20));       // 16 MB [B,H,S,D]
    short* Vt   = (short*)(ws + (56ull << 20));       // 16 MB [B,H,D,S]
    short* Obuf = Xbf;

    convert_f32_bf16<<<2048, 256, 0, stream>>>(x, Xbf, M_ * E_);
    transpose_convert<<<dim3(N1_ / 32, E_ / 32), dim3(32, 8), 0, stream>>>(w_attn, Wat, E_, N1_);
    transpose_convert<<<dim3(E_ / 32, E_ / 32), dim3(32, 8), 0, stream>>>(w_out, Wot, E_, E_);

    gemm_bt<0><<<dim3(N1_ / 128, M_ / 128), 256, 0, stream>>>(
        Xbf, Wat, b_attn, nullptr, Qb, Kb, Vt, E_, N1_);

    attn_kernel<<<dim3(8, 64), 512, 0, stream>>>(Qb, Kb, Vt, Obuf);

    gemm_bt<1><<<dim3(E_ / 128, M_ / 128), 256, 0, stream>>>(
        Obuf, Wot, b_out, out, nullptr, nullptr, nullptr, E_, E_);
}

// Round 3
// 221.876 us; speedup vs baseline: 1.6709x; 1.0254x over previous
//
#include <hip/hip_runtime.h>

typedef short bf16x8 __attribute__((ext_vector_type(8)));
typedef float f32x4 __attribute__((ext_vector_type(4)));
typedef float float4v __attribute__((ext_vector_type(4)));
typedef short short4v __attribute__((ext_vector_type(4)));

#define B_ 4
#define S_ 2048
#define E_ 1024
#define H_ 16
#define D_ 64
#define M_ (B_*S_)      // 8192
#define N1_ (3*E_)      // 3072

// fp32 -> bf16 round-to-nearest-even
__device__ inline short f2bs(float f) {
    unsigned u = __builtin_bit_cast(unsigned, f);
    unsigned r = u + 0x7fffu + ((u >> 16) & 1u);
    return (short)(r >> 16);
}
__device__ inline float exp2a(float x) {
    float r; asm("v_exp_f32 %0, %1" : "=v"(r) : "v"(x)); return r;
}
__device__ inline unsigned cvtpk(float a, float b) {
    unsigned r; asm("v_cvt_pk_bf16_f32 %0, %1, %2" : "=v"(r) : "v"(a), "v"(b)); return r;
}

__device__ inline const __attribute__((address_space(1))) void* gas(const void* p) {
    return (const __attribute__((address_space(1))) void*)p;
}
__device__ inline __attribute__((address_space(3))) void* las(void* p) {
    return (__attribute__((address_space(3))) void*)p;
}

// ---------------- elementwise fp32 -> bf16 ----------------
__global__ void convert_f32_bf16(const float* __restrict__ in, short* __restrict__ out, int n) {
    int tid = blockIdx.x * blockDim.x + threadIdx.x;
    int stride = gridDim.x * blockDim.x;
    for (int i = tid * 4; i < n; i += stride * 4) {
        float4v v = *(const float4v*)&in[i];
        short4v o;
        o[0] = f2bs(v[0]); o[1] = f2bs(v[1]); o[2] = f2bs(v[2]); o[3] = f2bs(v[3]);
        *(short4v*)&out[i] = o;
    }
}

// ---------------- tiled transpose + convert ----------------
__global__ void transpose_convert(const float* __restrict__ in, short* __restrict__ out,
                                  int rows, int cols) {
    __shared__ float t[32][33];
    int bx = blockIdx.x * 32;
    int by = blockIdx.y * 32;
    int tx = threadIdx.x, ty = threadIdx.y;  // (32, 8)
#pragma unroll
    for (int i = 0; i < 4; ++i)
        t[ty + i * 8][tx] = in[(size_t)(by + ty + i * 8) * cols + bx + tx];
    __syncthreads();
#pragma unroll
    for (int i = 0; i < 4; ++i)
        out[(size_t)(bx + ty + i * 8) * rows + by + tx] = f2bs(t[tx][ty + i * 8]);
}

// ================= 256x256 8-phase GEMM (QKV) =================
// C = A[M][K] * Bt[N][K]^T, scatter epilogue to Q/K/V.
// 8 waves (2M x 4N), BK=64, 128KiB LDS dbuf, st_16x32 swizzle, counted vmcnt.
#define MFMA16(Q) \
    _Pragma("unroll") for (int mf = 0; mf < 2; ++mf) \
    _Pragma("unroll") for (int nf = 0; nf < 4; ++nf) { \
        acc[(Q)*2+mf][nf] = __builtin_amdgcn_mfma_f32_16x16x32_bf16(af[mf][0], bfrag[nf][0], acc[(Q)*2+mf][nf], 0, 0, 0); \
        acc[(Q)*2+mf][nf] = __builtin_amdgcn_mfma_f32_16x16x32_bf16(af[mf][1], bfrag[nf][1], acc[(Q)*2+mf][nf], 0, 0, 0); \
    }

#define PHASE(Q, STAGE_STMT, WAITV) do { \
    bf16x8 af[2][2]; \
    _Pragma("unroll") for (int mf = 0; mf < 2; ++mf) \
    _Pragma("unroll") for (int ks = 0; ks < 2; ++ks) { \
        int r = (Q)*32 + mf*16 + li; \
        af[mf][ks] = *(const bf16x8*)(lA + r*128 + ((ks*64 + g*16) ^ (((r>>2)&1)<<5))); \
    } \
    STAGE_STMT; \
    __builtin_amdgcn_s_barrier(); \
    asm volatile("s_waitcnt lgkmcnt(0)" ::: "memory"); \
    __builtin_amdgcn_sched_barrier(0); \
    __builtin_amdgcn_s_setprio(1); \
    MFMA16(Q); \
    __builtin_amdgcn_s_setprio(0); \
    WAITV; \
    __builtin_amdgcn_s_barrier(); \
} while (0)

#define VMW(n) asm volatile("s_waitcnt vmcnt(" #n ")" ::: "memory")
#define NOP_ ((void)0)

__global__ __launch_bounds__(512, 2) void gemm256_qkv(
    const short* __restrict__ A, const short* __restrict__ Bt,
    const float* __restrict__ bias,
    short* __restrict__ Qb, short* __restrict__ Kb, short* __restrict__ Vt) {
    __shared__ __attribute__((aligned(16))) short lds[2][2][2][8192];  // [buf][A/B][half][128x64]
    const int tid = threadIdx.x;
    const int lane = tid & 63;
    const int wid = tid >> 6;
    const int li = lane & 15, g = lane >> 4;
    const int wr = wid >> 2, wc = wid & 3;
    const int Kdim = E_;  // 1024
    const int NT = Kdim >> 6;  // 16 K-tiles

    // bijective XCD swizzle: nwg=384, 384/8=48
    const int id = blockIdx.x;
    const int swz = (id & 7) * 48 + (id >> 3);
    const int bx = swz % 12, by = swz / 12;
    const int row0 = by * 256, col0 = bx * 256;

    // staging lane geometry (linear LDS dest, inverse-swizzled global src)
    const int rstage = wid * 8 + (lane >> 3);                 // row-in-seg (0..63)
    const int cstage = ((lane & 7) << 4) ^ (lane & 32);       // byte-in-row

    auto stageA = [&](int buf, int kt, int seg) {
#pragma unroll
        for (int h = 0; h < 2; ++h) {
            const char* src = (const char*)A +
                ((size_t)(row0 + h * 128 + seg * 64 + rstage) * Kdim + kt * 64) * 2 + cstage;
            char* dst = (char*)&lds[buf][0][h][0] + seg * 8192 + wid * 1024;
            __builtin_amdgcn_global_load_lds(gas(src), las(dst), 16, 0, 0);
        }
    };
    auto stageB = [&](int buf, int kt, int h) {
#pragma unroll
        for (int seg = 0; seg < 2; ++seg) {
            const char* src = (const char*)Bt +
                ((size_t)(col0 + h * 128 + seg * 64 + rstage) * Kdim + kt * 64) * 2 + cstage;
            char* dst = (char*)&lds[buf][1][h][0] + seg * 8192 + wid * 1024;
            __builtin_amdgcn_global_load_lds(gas(src), las(dst), 16, 0, 0);
        }
    };

    f32x4 acc[8][4];
#pragma unroll
    for (int m = 0; m < 8; ++m)
#pragma unroll
        for (int n = 0; n < 4; ++n) acc[m][n] = (f32x4){0.f, 0.f, 0.f, 0.f};

    // prologue: tile 0 -> buf 0, full drain (once)
    stageB(0, 0, 0);
    stageB(0, 0, 1);
    stageA(0, 0, 0);
    stageA(0, 0, 1);
    asm volatile("s_waitcnt vmcnt(0)" ::: "memory");
    __syncthreads();

    const int bc = (wc & 1) * 64;
    for (int t = 0; t < NT; ++t) {
        const int cur = t & 1;
        const int nb = cur ^ 1;
        const int tn = t + 1;
        const bool st = (tn < NT);
        const char* lA = (const char*)&lds[cur][0][wr][0];
        const char* lB = (const char*)&lds[cur][1][wc >> 1][0];

        bf16x8 bfrag[4][2];
#pragma unroll
        for (int nf = 0; nf < 4; ++nf)
#pragma unroll
            for (int ks = 0; ks < 2; ++ks) {
                int r = bc + nf * 16 + li;
                bfrag[nf][ks] = *(const bf16x8*)(lB + r * 128 + ((ks * 64 + g * 16) ^ (((r >> 2) & 1) << 5)));
            }
        if (st) {
            PHASE(0, stageB(nb, tn, 0), NOP_);
            PHASE(1, stageB(nb, tn, 1), VMW(4));
            PHASE(2, stageA(nb, tn, 0), NOP_);
            PHASE(3, stageA(nb, tn, 1), VMW(2));
        } else {
            PHASE(0, NOP_, NOP_);
            PHASE(1, NOP_, VMW(0));
            PHASE(2, NOP_, NOP_);
            PHASE(3, NOP_, NOP_);
        }
    }

    // epilogue: scatter to Q/K/V (C layout: col = lane&15, row = (lane>>4)*4 + j)
#pragma unroll
    for (int nf = 0; nf < 4; ++nf) {
        int ncol = col0 + wc * 64 + nf * 16 + li;
        float bv = bias[ncol];
        int part = ncol >> 10;
        int rem = ncol & 1023;
        int h = rem >> 6;
        int d = rem & 63;
#pragma unroll
        for (int mi = 0; mi < 8; ++mi) {
            int rbase = row0 + wr * 128 + mi * 16 + 4 * g;
#pragma unroll
            for (int j = 0; j < 4; ++j) {
                int row = rbase + j;
                int bb = row >> 11;
                int ss = row & 2047;
                short o = f2bs(acc[mi][nf][j] + bv);
                if (part == 0)
                    Qb[((size_t)(bb * H_ + h) * S_ + ss) * D_ + d] = o;
                else if (part == 1)
                    Kb[((size_t)(bb * H_ + h) * S_ + ss) * D_ + d] = o;
                else
                    Vt[((size_t)(bb * H_ + h) * D_ + d) * S_ + ss] = o;
            }
        }
    }
}

// ---------------- bf16 GEMM, 128x128 tile (out-proj) ----------------
__global__ __launch_bounds__(256, 2) void gemm_bt_out(
    const short* __restrict__ A, const short* __restrict__ Bt,
    const float* __restrict__ bias, float* __restrict__ Cf,
    int Kdim, int Ndim) {
    __shared__ __attribute__((aligned(16))) short As[128 * 32];
    __shared__ __attribute__((aligned(16))) short Bs[128 * 32];
    const int lane = threadIdx.x & 63;
    const int wv = threadIdx.x >> 6;
    const int row0 = blockIdx.y * 128;
    const int col0 = blockIdx.x * 128;
    const int wr = (wv >> 1) * 64;
    const int wc = (wv & 1) * 64;
    const int li = lane & 15;
    const int g = lane >> 4;
    const int lr = lane >> 2;
    const int lk = (lane & 3) * 8;

    f32x4 acc[4][4];
#pragma unroll
    for (int m = 0; m < 4; ++m)
#pragma unroll
        for (int n = 0; n < 4; ++n) acc[m][n] = (f32x4){0.f, 0.f, 0.f, 0.f};

    for (int k0 = 0; k0 < Kdim; k0 += 32) {
#pragma unroll
        for (int i = 0; i < 2; ++i) {
            int cc = wv * 2 + i;
            const short* ga = A + (size_t)(row0 + cc * 16 + lr) * Kdim + k0 + lk;
            __builtin_amdgcn_global_load_lds(gas(ga), las(&As[cc * 512]), 16, 0, 0);
            const short* gb = Bt + (size_t)(col0 + cc * 16 + lr) * Kdim + k0 + lk;
            __builtin_amdgcn_global_load_lds(gas(gb), las(&Bs[cc * 512]), 16, 0, 0);
        }
        __syncthreads();
        bf16x8 af[4], bfr[4];
#pragma unroll
        for (int m = 0; m < 4; ++m) af[m] = *(const bf16x8*)&As[(wr + 16 * m + li) * 32 + g * 8];
#pragma unroll
        for (int n = 0; n < 4; ++n) bfr[n] = *(const bf16x8*)&Bs[(wc + 16 * n + li) * 32 + g * 8];
#pragma unroll
        for (int m = 0; m < 4; ++m)
#pragma unroll
            for (int n = 0; n < 4; ++n)
                acc[m][n] = __builtin_amdgcn_mfma_f32_16x16x32_bf16(af[m], bfr[n], acc[m][n], 0, 0, 0);
        __syncthreads();
    }

#pragma unroll
    for (int n = 0; n < 4; ++n) {
        int ncol = col0 + wc + 16 * n + li;
        float bv = bias[ncol];
#pragma unroll
        for (int m = 0; m < 4; ++m) {
            int rbase = row0 + wr + 16 * m + 4 * g;
#pragma unroll
            for (int j = 0; j < 4; ++j)
                Cf[(size_t)(rbase + j) * Ndim + ncol] = acc[m][n][j] + bv;
        }
    }
}

// ---------------- causal flash attention (R1 structure) ----------------
__global__ __launch_bounds__(512, 4) void attn_kernel(
    const short* __restrict__ Qb, const short* __restrict__ Kb,
    const short* __restrict__ Vt, short* __restrict__ Ob) {
    __shared__ __attribute__((aligned(16))) short Kl[4096];
    __shared__ __attribute__((aligned(16))) short Vl[4096];
    __shared__ __attribute__((aligned(16))) short Plds[8][1024];
    const int lane = threadIdx.x & 63;
    const int wv = threadIdx.x >> 6;
    const int li = lane & 15;
    const int g = lane >> 4;
    const int d0 = blockIdx.x + blockIdx.y * 8;
    const int X = d0 & 7, kk = d0 >> 3;
    const int bh = X * 8 + (kk >> 3);
    const int pp = kk & 7;
    const int bb = bh >> 4, hh = bh & 15;
    const short* Qh = Qb + (size_t)bh * (S_ * D_);
    const short* Kh = Kb + (size_t)bh * (S_ * D_);
    const short* Vh = Vt + (size_t)bh * (D_ * S_);
    const float CEXP = 0.18033688011112042f;  // (1/8)*log2(e)
    bf16x8 ONES;
#pragma unroll
    for (int i = 0; i < 8; ++i) ONES[i] = (short)0x3F80;

    const int r8 = lane >> 3;
    const int c16 = ((lane & 7) ^ r8) << 4;
    const int strow = wv * 8 + r8;
    char* Pb = (char*)&Plds[wv][0];
    const int lsw = (li & 7) << 4;

    for (int t = 0; t < 2; ++t) {
        const int qt = t ? (15 - pp) : pp;
        const int q0 = qt * 128 + wv * 16;
        bf16x8 qa[2];
#pragma unroll
        for (int c = 0; c < 2; ++c)
            qa[c] = *(const bf16x8*)&Qh[(size_t)(q0 + li) * D_ + c * 32 + g * 8];
        f32x4 acc[4];
        f32x4 lsum = (f32x4){0.f, 0.f, 0.f, 0.f};
#pragma unroll
        for (int dc = 0; dc < 4; ++dc) acc[dc] = (f32x4){0.f, 0.f, 0.f, 0.f};
        float mrow[4], mrowC[4];
#pragma unroll
        for (int j = 0; j < 4; ++j) { mrow[j] = -3e38f; mrowC[j] = 0.f; }

        const int nw = (q0 + 79) >> 6;
        const int nt = (qt * 128 + 191) >> 6;

        for (int it = 0; it < nt; ++it) {
            const int kt0 = it * 64;
            {
                const char* gk = (const char*)Kh + (size_t)(kt0 + strow) * 128 + c16;
                __builtin_amdgcn_global_load_lds(gas(gk), las((char*)Kl + wv * 1024), 16, 0, 0);
                const char* gv = (const char*)Vh + (size_t)strow * (S_ * 2) + (size_t)kt0 * 2 + c16;
                __builtin_amdgcn_global_load_lds(gas(gv), las((char*)Vl + wv * 1024), 16, 0, 0);
            }
            __syncthreads();
            if (it < nw) {
                const bool bmask = (it == nw - 1);
                bf16x8 kf[4][2];
#pragma unroll
                for (int kc = 0; kc < 4; ++kc)
#pragma unroll
                    for (int c = 0; c < 2; ++c)
                        kf[kc][c] = *(const bf16x8*)((const char*)Kl + (kc * 16 + li) * 128 +
                                                     ((c * 64 + g * 16) ^ lsw));
                f32x4 sc4[4];
#pragma unroll
                for (int kc = 0; kc < 4; ++kc) {
                    f32x4 z = (f32x4){0.f, 0.f, 0.f, 0.f};
                    z = __builtin_amdgcn_mfma_f32_16x16x32_bf16(qa[0], kf[kc][0], z, 0, 0, 0);
                    z = __builtin_amdgcn_mfma_f32_16x16x32_bf16(qa[1], kf[kc][1], z, 0, 0, 0);
                    sc4[kc] = z;
                }
                if (bmask) {
#pragma unroll
                    for (int kc = 0; kc < 4; ++kc) {
                        int key = kt0 + kc * 16 + li;
#pragma unroll
                        for (int j = 0; j < 4; ++j) {
                            int qr = q0 + 4 * g + j;
                            sc4[kc][j] = (key > qr) ? -3e38f : sc4[kc][j];
                        }
                    }
                }
                float tmax[4];
#pragma unroll
                for (int j = 0; j < 4; ++j)
                    tmax[j] = fmaxf(fmaxf(sc4[0][j], sc4[1][j]), fmaxf(sc4[2][j], sc4[3][j]));
#pragma unroll
                for (int msk = 1; msk < 16; msk <<= 1)
#pragma unroll
                    for (int j = 0; j < 4; ++j)
                        tmax[j] = fmaxf(tmax[j], __shfl_xor(tmax[j], msk, 64));
                bool need = (tmax[0] > mrow[0]) | (tmax[1] > mrow[1]) |
                            (tmax[2] > mrow[2]) | (tmax[3] > mrow[3]);
                if (__ballot((int)need) != 0ull) {
#pragma unroll
                    for (int j = 0; j < 4; ++j) {
                        float mn = fmaxf(mrow[j], tmax[j]);
                        float sf = exp2a((mrow[j] - mn) * CEXP);
                        mrow[j] = mn;
                        mrowC[j] = mn * CEXP;
                        lsum[j] *= sf;
#pragma unroll
                        for (int dc = 0; dc < 4; ++dc) acc[dc][j] *= sf;
                    }
                }
#pragma unroll
                for (int j = 0; j < 4; ++j) {
                    const int rowb = (4 * g + j) * 128;
                    const int rx = ((4 * g + j) & 7) << 4;
#pragma unroll
                    for (int kp = 0; kp < 2; ++kp) {
                        float p0 = exp2a(fmaf(sc4[2 * kp][j], CEXP, -mrowC[j]));
                        float p1 = exp2a(fmaf(sc4[2 * kp + 1][j], CEXP, -mrowC[j]));
                        unsigned u = cvtpk(p0, p1);
                        *(short*)(Pb + rowb + ((kp * 64 + li * 2) ^ rx)) = (short)u;
                        *(short*)(Pb + rowb + ((kp * 64 + 32 + li * 2) ^ rx)) = (short)(u >> 16);
                    }
                }
                bf16x8 vf[4][2];
#pragma unroll
                for (int dc = 0; dc < 4; ++dc)
#pragma unroll
                    for (int c = 0; c < 2; ++c)
                        vf[dc][c] = *(const bf16x8*)((const char*)Vl + (dc * 16 + li) * 128 +
                                                     ((c * 64 + g * 16) ^ lsw));
                asm volatile("s_waitcnt lgkmcnt(0)" ::: "memory");
                __builtin_amdgcn_sched_barrier(0);
                bf16x8 pa[2];
#pragma unroll
                for (int c = 0; c < 2; ++c)
                    pa[c] = *(const bf16x8*)(Pb + li * 128 + ((c * 64 + g * 16) ^ lsw));
#pragma unroll
                for (int dc = 0; dc < 4; ++dc) {
                    acc[dc] = __builtin_amdgcn_mfma_f32_16x16x32_bf16(pa[0], vf[dc][0], acc[dc], 0, 0, 0);
                    acc[dc] = __builtin_amdgcn_mfma_f32_16x16x32_bf16(pa[1], vf[dc][1], acc[dc], 0, 0, 0);
                }
                lsum = __builtin_amdgcn_mfma_f32_16x16x32_bf16(pa[0], ONES, lsum, 0, 0, 0);
                lsum = __builtin_amdgcn_mfma_f32_16x16x32_bf16(pa[1], ONES, lsum, 0, 0, 0);
            }
            __syncthreads();
        }
        float rl[4];
#pragma unroll
        for (int j = 0; j < 4; ++j) rl[j] = __builtin_amdgcn_rcpf(lsum[j]);
#pragma unroll
        for (int dc = 0; dc < 4; ++dc)
#pragma unroll
            for (int j = 0; j < 4; ++j) {
                int sr = q0 + 4 * g + j;
                Ob[((size_t)(bb * S_ + sr)) * E_ + hh * 64 + dc * 16 + li] = f2bs(acc[dc][j] * rl[j]);
            }
    }
}

extern "C" void kernel_launch(void* const* d_in, const int* in_sizes, int n_in,
                              void* d_out, int out_size, void* d_ws, size_t ws_size,
                              hipStream_t stream) {
    const float* x      = (const float*)d_in[0];
    const float* w_attn = (const float*)d_in[1];
    const float* b_attn = (const float*)d_in[2];
    const float* w_out  = (const float*)d_in[3];
    const float* b_out  = (const float*)d_in[4];
    float* out = (float*)d_out;

    char* ws = (char*)d_ws;
    short* Xbf  = (short*)(ws);                       // 16 MB (reused as attn output)
    short* Wat  = (short*)(ws + (16ull << 20));       // 6 MB  [3072][1024]
    short* Wot  = (short*)(ws + (22ull << 20));       // 2 MB  [1024][1024]
    short* Qb   = (short*)(ws + (24ull << 20));       // 16 MB [B,H,S,D]
    short* Kb   = (short*)(ws + (40ull << 20));       // 16 MB [B,H,S,D]
    short* Vt   = (short*)(ws + (56ull << 20));       // 16 MB [B,H,D,S]
    short* Obuf = Xbf;

    convert_f32_bf16<<<2048, 256, 0, stream>>>(x, Xbf, M_ * E_);
    transpose_convert<<<dim3(N1_ / 32, E_ / 32), dim3(32, 8), 0, stream>>>(w_attn, Wat, E_, N1_);
    transpose_convert<<<dim3(E_ / 32, E_ / 32), dim3(32, 8), 0, stream>>>(w_out, Wot, E_, E_);

    gemm256_qkv<<<384, 512, 0, stream>>>(Xbf, Wat, b_attn, Qb, Kb, Vt);

    attn_kernel<<<dim3(8, 64), 512, 0, stream>>>(Qb, Kb, Vt, Obuf);

    gemm_bt_out<<<dim3(E_ / 128, M_ / 128), 256, 0, stream>>>(
        Obuf, Wot, b_out, out, E_, E_);
}

// Round 4
// 197.941 us; speedup vs baseline: 1.8729x; 1.1209x over previous
//
#include <hip/hip_runtime.h>

typedef short bf16x8 __attribute__((ext_vector_type(8)));
typedef float f32x4 __attribute__((ext_vector_type(4)));
typedef float float4v __attribute__((ext_vector_type(4)));
typedef short short4v __attribute__((ext_vector_type(4)));
typedef unsigned uint2v __attribute__((ext_vector_type(2)));

#define B_ 4
#define S_ 2048
#define E_ 1024
#define H_ 16
#define D_ 64
#define M_ (B_*S_)      // 8192
#define N1_ (3*E_)      // 3072

// fp32 -> bf16 round-to-nearest-even
__device__ inline short f2bs(float f) {
    unsigned u = __builtin_bit_cast(unsigned, f);
    unsigned r = u + 0x7fffu + ((u >> 16) & 1u);
    return (short)(r >> 16);
}
__device__ inline float exp2a(float x) {
    float r; asm("v_exp_f32 %0, %1" : "=v"(r) : "v"(x)); return r;
}
__device__ inline unsigned cvtpk(float a, float b) {
    unsigned r; asm("v_cvt_pk_bf16_f32 %0, %1, %2" : "=v"(r) : "v"(a), "v"(b)); return r;
}

__device__ inline const __attribute__((address_space(1))) void* gas(const void* p) {
    return (const __attribute__((address_space(1))) void*)p;
}
__device__ inline __attribute__((address_space(3))) void* las(void* p) {
    return (__attribute__((address_space(3))) void*)p;
}

// ---------------- elementwise fp32 -> bf16 ----------------
__global__ void convert_f32_bf16(const float* __restrict__ in, short* __restrict__ out, int n) {
    int tid = blockIdx.x * blockDim.x + threadIdx.x;
    int stride = gridDim.x * blockDim.x;
    for (int i = tid * 4; i < n; i += stride * 4) {
        float4v v = *(const float4v*)&in[i];
        short4v o;
        o[0] = f2bs(v[0]); o[1] = f2bs(v[1]); o[2] = f2bs(v[2]); o[3] = f2bs(v[3]);
        *(short4v*)&out[i] = o;
    }
}

// ---------------- tiled transpose + convert ----------------
__global__ void transpose_convert(const float* __restrict__ in, short* __restrict__ out,
                                  int rows, int cols) {
    __shared__ float t[32][33];
    int bx = blockIdx.x * 32;
    int by = blockIdx.y * 32;
    int tx = threadIdx.x, ty = threadIdx.y;  // (32, 8)
#pragma unroll
    for (int i = 0; i < 4; ++i)
        t[ty + i * 8][tx] = in[(size_t)(by + ty + i * 8) * cols + bx + tx];
    __syncthreads();
#pragma unroll
    for (int i = 0; i < 4; ++i)
        out[(size_t)(bx + ty + i * 8) * rows + by + tx] = f2bs(t[tx][ty + i * 8]);
}

// ================= 256x256 8-phase GEMM (QKV) =================
// Row-spread swizzle: byte-in-row ^= (row&7)<<4 (both sides).
// Epilogue: Q/K -> flat [8192][1024] row-major (coalesced); V -> [B,H,D,S] via
// packed dwordx2 (4 consecutive s per store).
#define MFMA16(Q) \
    _Pragma("unroll") for (int mf = 0; mf < 2; ++mf) \
    _Pragma("unroll") for (int nf = 0; nf < 4; ++nf) { \
        acc[(Q)*2+mf][nf] = __builtin_amdgcn_mfma_f32_16x16x32_bf16(af[mf][0], bfrag[nf][0], acc[(Q)*2+mf][nf], 0, 0, 0); \
        acc[(Q)*2+mf][nf] = __builtin_amdgcn_mfma_f32_16x16x32_bf16(af[mf][1], bfrag[nf][1], acc[(Q)*2+mf][nf], 0, 0, 0); \
    }

#define PHASE(Q, STAGE_STMT, WAITV) do { \
    bf16x8 af[2][2]; \
    _Pragma("unroll") for (int mf = 0; mf < 2; ++mf) \
    _Pragma("unroll") for (int ks = 0; ks < 2; ++ks) { \
        int r = (Q)*32 + mf*16 + li; \
        af[mf][ks] = *(const bf16x8*)(lA + r*128 + ((ks*64 + g*16) ^ ((r & 7) << 4))); \
    } \
    STAGE_STMT; \
    __builtin_amdgcn_s_barrier(); \
    asm volatile("s_waitcnt lgkmcnt(0)" ::: "memory"); \
    __builtin_amdgcn_sched_barrier(0); \
    __builtin_amdgcn_s_setprio(1); \
    MFMA16(Q); \
    __builtin_amdgcn_s_setprio(0); \
    WAITV; \
    __builtin_amdgcn_s_barrier(); \
} while (0)

#define VMW(n) asm volatile("s_waitcnt vmcnt(" #n ")" ::: "memory")
#define NOP_ ((void)0)

__global__ __launch_bounds__(512, 2) void gemm256_qkv(
    const short* __restrict__ A, const short* __restrict__ Bt,
    const float* __restrict__ bias,
    short* __restrict__ Qb, short* __restrict__ Kb, short* __restrict__ Vt) {
    __shared__ __attribute__((aligned(16))) short lds[2][2][2][8192];  // [buf][A/B][half][128x64]
    const int tid = threadIdx.x;
    const int lane = tid & 63;
    const int wid = tid >> 6;
    const int li = lane & 15, g = lane >> 4;
    const int wr = wid >> 2, wc = wid & 3;
    const int Kdim = E_;       // 1024
    const int NT = Kdim >> 6;  // 16 K-tiles

    // bijective XCD swizzle: nwg=384, 384/8=48
    const int id = blockIdx.x;
    const int swz = (id & 7) * 48 + (id >> 3);
    const int bx = swz % 12, by = swz / 12;
    const int row0 = by * 256, col0 = bx * 256;

    // staging lane geometry: linear LDS dest, inverse-swizzled global src.
    // LDS row (within 64-row seg) = wid*8 + (lane>>3); row&7 = (lane>>3)&7.
    const int rstage = wid * 8 + (lane >> 3);
    const int cstage = (((lane & 7) ^ ((lane >> 3) & 7)) << 4);

    auto stageA = [&](int buf, int kt, int seg) {
#pragma unroll
        for (int h = 0; h < 2; ++h) {
            const char* src = (const char*)A +
                ((size_t)(row0 + h * 128 + seg * 64 + rstage) * Kdim + kt * 64) * 2 + cstage;
            char* dst = (char*)&lds[buf][0][h][0] + seg * 8192 + wid * 1024;
            __builtin_amdgcn_global_load_lds(gas(src), las(dst), 16, 0, 0);
        }
    };
    auto stageB = [&](int buf, int kt, int h) {
#pragma unroll
        for (int seg = 0; seg < 2; ++seg) {
            const char* src = (const char*)Bt +
                ((size_t)(col0 + h * 128 + seg * 64 + rstage) * Kdim + kt * 64) * 2 + cstage;
            char* dst = (char*)&lds[buf][1][h][0] + seg * 8192 + wid * 1024;
            __builtin_amdgcn_global_load_lds(gas(src), las(dst), 16, 0, 0);
        }
    };

    f32x4 acc[8][4];
#pragma unroll
    for (int m = 0; m < 8; ++m)
#pragma unroll
        for (int n = 0; n < 4; ++n) acc[m][n] = (f32x4){0.f, 0.f, 0.f, 0.f};

    // prologue: tile 0 -> buf 0, full drain (once)
    stageB(0, 0, 0);
    stageB(0, 0, 1);
    stageA(0, 0, 0);
    stageA(0, 0, 1);
    asm volatile("s_waitcnt vmcnt(0)" ::: "memory");
    __syncthreads();

    const int bc = (wc & 1) * 64;
    for (int t = 0; t < NT; ++t) {
        const int cur = t & 1;
        const int nb = cur ^ 1;
        const int tn = t + 1;
        const bool st = (tn < NT);
        const char* lA = (const char*)&lds[cur][0][wr][0];
        const char* lB = (const char*)&lds[cur][1][wc >> 1][0];

        bf16x8 bfrag[4][2];
#pragma unroll
        for (int nf = 0; nf < 4; ++nf)
#pragma unroll
            for (int ks = 0; ks < 2; ++ks) {
                int r = bc + nf * 16 + li;
                bfrag[nf][ks] = *(const bf16x8*)(lB + r * 128 + ((ks * 64 + g * 16) ^ ((r & 7) << 4)));
            }
        if (st) {
            PHASE(0, stageB(nb, tn, 0), NOP_);
            PHASE(1, stageB(nb, tn, 1), VMW(4));
            PHASE(2, stageA(nb, tn, 0), NOP_);
            PHASE(3, stageA(nb, tn, 1), VMW(2));
        } else {
            PHASE(0, NOP_, NOP_);
            PHASE(1, NOP_, VMW(0));
            PHASE(2, NOP_, NOP_);
            PHASE(3, NOP_, NOP_);
        }
    }

    // ---- epilogue (C layout: col = lane&15, row = (lane>>4)*4 + j) ----
    if (col0 < 2048) {
        // Q or K part: flat [8192][1024] row-major, coalesced 2B stores
        short* Dst = (col0 < 1024) ? Qb : Kb;
#pragma unroll
        for (int nf = 0; nf < 4; ++nf) {
            int ncolg = col0 + wc * 64 + nf * 16 + li;
            float bv = bias[ncolg];
            int ncol = ncolg & 1023;
#pragma unroll
            for (int mi = 0; mi < 8; ++mi) {
                int rbase = row0 + wr * 128 + mi * 16 + 4 * g;
#pragma unroll
                for (int j = 0; j < 4; ++j)
                    Dst[(size_t)(rbase + j) * E_ + ncol] = f2bs(acc[mi][nf][j] + bv);
            }
        }
    } else {
        // V part: [B,H,D,S], 4 consecutive s packed into one dwordx2 store
#pragma unroll
        for (int nf = 0; nf < 4; ++nf) {
            int ncolg = col0 + wc * 64 + nf * 16 + li;
            float bv = bias[ncolg];
            int rem = ncolg & 1023;
            int h = rem >> 6, d = rem & 63;
#pragma unroll
            for (int mi = 0; mi < 8; ++mi) {
                int s0 = row0 + wr * 128 + mi * 16 + 4 * g;
                int bb2 = s0 >> 11;
                int ss = s0 & 2047;
                uint2v p;
                p[0] = cvtpk(acc[mi][nf][0] + bv, acc[mi][nf][1] + bv);
                p[1] = cvtpk(acc[mi][nf][2] + bv, acc[mi][nf][3] + bv);
                *(uint2v*)&Vt[((size_t)(bb2 * H_ + h) * D_ + d) * S_ + ss] = p;
            }
        }
    }
}

// ---------------- bf16 GEMM, 128x128 tile (out-proj) ----------------
__global__ __launch_bounds__(256, 2) void gemm_bt_out(
    const short* __restrict__ A, const short* __restrict__ Bt,
    const float* __restrict__ bias, float* __restrict__ Cf,
    int Kdim, int Ndim) {
    __shared__ __attribute__((aligned(16))) short As[128 * 32];
    __shared__ __attribute__((aligned(16))) short Bs[128 * 32];
    const int lane = threadIdx.x & 63;
    const int wv = threadIdx.x >> 6;
    const int row0 = blockIdx.y * 128;
    const int col0 = blockIdx.x * 128;
    const int wr = (wv >> 1) * 64;
    const int wc = (wv & 1) * 64;
    const int li = lane & 15;
    const int g = lane >> 4;
    const int lr = lane >> 2;
    const int lk = (lane & 3) * 8;

    f32x4 acc[4][4];
#pragma unroll
    for (int m = 0; m < 4; ++m)
#pragma unroll
        for (int n = 0; n < 4; ++n) acc[m][n] = (f32x4){0.f, 0.f, 0.f, 0.f};

    for (int k0 = 0; k0 < Kdim; k0 += 32) {
#pragma unroll
        for (int i = 0; i < 2; ++i) {
            int cc = wv * 2 + i;
            const short* ga = A + (size_t)(row0 + cc * 16 + lr) * Kdim + k0 + lk;
            __builtin_amdgcn_global_load_lds(gas(ga), las(&As[cc * 512]), 16, 0, 0);
            const short* gb = Bt + (size_t)(col0 + cc * 16 + lr) * Kdim + k0 + lk;
            __builtin_amdgcn_global_load_lds(gas(gb), las(&Bs[cc * 512]), 16, 0, 0);
        }
        __syncthreads();
        bf16x8 af[4], bfr[4];
#pragma unroll
        for (int m = 0; m < 4; ++m) af[m] = *(const bf16x8*)&As[(wr + 16 * m + li) * 32 + g * 8];
#pragma unroll
        for (int n = 0; n < 4; ++n) bfr[n] = *(const bf16x8*)&Bs[(wc + 16 * n + li) * 32 + g * 8];
#pragma unroll
        for (int m = 0; m < 4; ++m)
#pragma unroll
            for (int n = 0; n < 4; ++n)
                acc[m][n] = __builtin_amdgcn_mfma_f32_16x16x32_bf16(af[m], bfr[n], acc[m][n], 0, 0, 0);
        __syncthreads();
    }

#pragma unroll
    for (int n = 0; n < 4; ++n) {
        int ncol = col0 + wc + 16 * n + li;
        float bv = bias[ncol];
#pragma unroll
        for (int m = 0; m < 4; ++m) {
            int rbase = row0 + wr + 16 * m + 4 * g;
#pragma unroll
            for (int j = 0; j < 4; ++j)
                Cf[(size_t)(rbase + j) * Ndim + ncol] = acc[m][n][j] + bv;
        }
    }
}

// ---------------- causal flash attention ----------------
// Q,K now flat [B,S,H*D] row-major (stride E_); V stays [B,H,D,S].
__global__ __launch_bounds__(512, 4) void attn_kernel(
    const short* __restrict__ Qb, const short* __restrict__ Kb,
    const short* __restrict__ Vt, short* __restrict__ Ob) {
    __shared__ __attribute__((aligned(16))) short Kl[4096];
    __shared__ __attribute__((aligned(16))) short Vl[4096];
    __shared__ __attribute__((aligned(16))) short Plds[8][1024];
    const int lane = threadIdx.x & 63;
    const int wv = threadIdx.x >> 6;
    const int li = lane & 15;
    const int g = lane >> 4;
    const int d0 = blockIdx.x + blockIdx.y * 8;
    const int X = d0 & 7, kk = d0 >> 3;
    const int bh = X * 8 + (kk >> 3);
    const int pp = kk & 7;
    const int bb = bh >> 4, hh = bh & 15;
    const short* Qh = Qb + (size_t)bb * (S_ * E_) + hh * 64;
    const short* Kh = Kb + (size_t)bb * (S_ * E_) + hh * 64;
    const short* Vh = Vt + (size_t)bh * (D_ * S_);
    const float CEXP = 0.18033688011112042f;  // (1/8)*log2(e)
    bf16x8 ONES;
#pragma unroll
    for (int i = 0; i < 8; ++i) ONES[i] = (short)0x3F80;

    const int r8 = lane >> 3;
    const int c16 = ((lane & 7) ^ r8) << 4;
    const int strow = wv * 8 + r8;
    char* Pb = (char*)&Plds[wv][0];
    const int lsw = (li & 7) << 4;

    for (int t = 0; t < 2; ++t) {
        const int qt = t ? (15 - pp) : pp;
        const int q0 = qt * 128 + wv * 16;
        bf16x8 qa[2];
#pragma unroll
        for (int c = 0; c < 2; ++c)
            qa[c] = *(const bf16x8*)&Qh[(size_t)(q0 + li) * E_ + c * 32 + g * 8];
        f32x4 acc[4];
        f32x4 lsum = (f32x4){0.f, 0.f, 0.f, 0.f};
#pragma unroll
        for (int dc = 0; dc < 4; ++dc) acc[dc] = (f32x4){0.f, 0.f, 0.f, 0.f};
        float mrow[4], mrowC[4];
#pragma unroll
        for (int j = 0; j < 4; ++j) { mrow[j] = -3e38f; mrowC[j] = 0.f; }

        const int nw = (q0 + 79) >> 6;
        const int nt = (qt * 128 + 191) >> 6;

        for (int it = 0; it < nt; ++it) {
            const int kt0 = it * 64;
            {
                const char* gk = (const char*)(Kh + (size_t)(kt0 + strow) * E_) + c16;
                __builtin_amdgcn_global_load_lds(gas(gk), las((char*)Kl + wv * 1024), 16, 0, 0);
                const char* gv = (const char*)Vh + (size_t)strow * (S_ * 2) + (size_t)kt0 * 2 + c16;
                __builtin_amdgcn_global_load_lds(gas(gv), las((char*)Vl + wv * 1024), 16, 0, 0);
            }
            __syncthreads();
            if (it < nw) {
                const bool bmask = (it == nw - 1);
                bf16x8 kf[4][2];
#pragma unroll
                for (int kc = 0; kc < 4; ++kc)
#pragma unroll
                    for (int c = 0; c < 2; ++c)
                        kf[kc][c] = *(const bf16x8*)((const char*)Kl + (kc * 16 + li) * 128 +
                                                     ((c * 64 + g * 16) ^ lsw));
                f32x4 sc4[4];
#pragma unroll
                for (int kc = 0; kc < 4; ++kc) {
                    f32x4 z = (f32x4){0.f, 0.f, 0.f, 0.f};
                    z = __builtin_amdgcn_mfma_f32_16x16x32_bf16(qa[0], kf[kc][0], z, 0, 0, 0);
                    z = __builtin_amdgcn_mfma_f32_16x16x32_bf16(qa[1], kf[kc][1], z, 0, 0, 0);
                    sc4[kc] = z;
                }
                if (bmask) {
#pragma unroll
                    for (int kc = 0; kc < 4; ++kc) {
                        int key = kt0 + kc * 16 + li;
#pragma unroll
                        for (int j = 0; j < 4; ++j) {
                            int qr = q0 + 4 * g + j;
                            sc4[kc][j] = (key > qr) ? -3e38f : sc4[kc][j];
                        }
                    }
                }
                float tmax[4];
#pragma unroll
                for (int j = 0; j < 4; ++j)
                    tmax[j] = fmaxf(fmaxf(sc4[0][j], sc4[1][j]), fmaxf(sc4[2][j], sc4[3][j]));
#pragma unroll
                for (int msk = 1; msk < 16; msk <<= 1)
#pragma unroll
                    for (int j = 0; j < 4; ++j)
                        tmax[j] = fmaxf(tmax[j], __shfl_xor(tmax[j], msk, 64));
                bool need = (tmax[0] > mrow[0]) | (tmax[1] > mrow[1]) |
                            (tmax[2] > mrow[2]) | (tmax[3] > mrow[3]);
                if (__ballot((int)need) != 0ull) {
#pragma unroll
                    for (int j = 0; j < 4; ++j) {
                        float mn = fmaxf(mrow[j], tmax[j]);
                        float sf = exp2a((mrow[j] - mn) * CEXP);
                        mrow[j] = mn;
                        mrowC[j] = mn * CEXP;
                        lsum[j] *= sf;
#pragma unroll
                        for (int dc = 0; dc < 4; ++dc) acc[dc][j] *= sf;
                    }
                }
#pragma unroll
                for (int j = 0; j < 4; ++j) {
                    const int rowb = (4 * g + j) * 128;
                    const int rx = ((4 * g + j) & 7) << 4;
#pragma unroll
                    for (int kp = 0; kp < 2; ++kp) {
                        float p0 = exp2a(fmaf(sc4[2 * kp][j], CEXP, -mrowC[j]));
                        float p1 = exp2a(fmaf(sc4[2 * kp + 1][j], CEXP, -mrowC[j]));
                        unsigned u = cvtpk(p0, p1);
                        *(short*)(Pb + rowb + ((kp * 64 + li * 2) ^ rx)) = (short)u;
                        *(short*)(Pb + rowb + ((kp * 64 + 32 + li * 2) ^ rx)) = (short)(u >> 16);
                    }
                }
                bf16x8 vf[4][2];
#pragma unroll
                for (int dc = 0; dc < 4; ++dc)
#pragma unroll
                    for (int c = 0; c < 2; ++c)
                        vf[dc][c] = *(const bf16x8*)((const char*)Vl + (dc * 16 + li) * 128 +
                                                     ((c * 64 + g * 16) ^ lsw));
                asm volatile("s_waitcnt lgkmcnt(0)" ::: "memory");
                __builtin_amdgcn_sched_barrier(0);
                bf16x8 pa[2];
#pragma unroll
                for (int c = 0; c < 2; ++c)
                    pa[c] = *(const bf16x8*)(Pb + li * 128 + ((c * 64 + g * 16) ^ lsw));
#pragma unroll
                for (int dc = 0; dc < 4; ++dc) {
                    acc[dc] = __builtin_amdgcn_mfma_f32_16x16x32_bf16(pa[0], vf[dc][0], acc[dc], 0, 0, 0);
                    acc[dc] = __builtin_amdgcn_mfma_f32_16x16x32_bf16(pa[1], vf[dc][1], acc[dc], 0, 0, 0);
                }
                lsum = __builtin_amdgcn_mfma_f32_16x16x32_bf16(pa[0], ONES, lsum, 0, 0, 0);
                lsum = __builtin_amdgcn_mfma_f32_16x16x32_bf16(pa[1], ONES, lsum, 0, 0, 0);
            }
            __syncthreads();
        }
        float rl[4];
#pragma unroll
        for (int j = 0; j < 4; ++j) rl[j] = __builtin_amdgcn_rcpf(lsum[j]);
#pragma unroll
        for (int dc = 0; dc < 4; ++dc)
#pragma unroll
            for (int j = 0; j < 4; ++j) {
                int sr = q0 + 4 * g + j;
                Ob[((size_t)(bb * S_ + sr)) * E_ + hh * 64 + dc * 16 + li] = f2bs(acc[dc][j] * rl[j]);
            }
    }
}

extern "C" void kernel_launch(void* const* d_in, const int* in_sizes, int n_in,
                              void* d_out, int out_size, void* d_ws, size_t ws_size,
                              hipStream_t stream) {
    const float* x      = (const float*)d_in[0];
    const float* w_attn = (const float*)d_in[1];
    const float* b_attn = (const float*)d_in[2];
    const float* w_out  = (const float*)d_in[3];
    const float* b_out  = (const float*)d_in[4];
    float* out = (float*)d_out;

    char* ws = (char*)d_ws;
    short* Xbf  = (short*)(ws);                       // 16 MB (reused as attn output)
    short* Wat  = (short*)(ws + (16ull << 20));       // 6 MB  [3072][1024]
    short* Wot  = (short*)(ws + (22ull << 20));       // 2 MB  [1024][1024]
    short* Qb   = (short*)(ws + (24ull << 20));       // 16 MB flat [8192][1024]
    short* Kb   = (short*)(ws + (40ull << 20));       // 16 MB flat [8192][1024]
    short* Vt   = (short*)(ws + (56ull << 20));       // 16 MB [B,H,D,S]
    short* Obuf = Xbf;

    convert_f32_bf16<<<2048, 256, 0, stream>>>(x, Xbf, M_ * E_);
    transpose_convert<<<dim3(N1_ / 32, E_ / 32), dim3(32, 8), 0, stream>>>(w_attn, Wat, E_, N1_);
    transpose_convert<<<dim3(E_ / 32, E_ / 32), dim3(32, 8), 0, stream>>>(w_out, Wot, E_, E_);

    gemm256_qkv<<<384, 512, 0, stream>>>(Xbf, Wat, b_attn, Qb, Kb, Vt);

    attn_kernel<<<dim3(8, 64), 512, 0, stream>>>(Qb, Kb, Vt, Obuf);

    gemm_bt_out<<<dim3(E_ / 128, M_ / 128), 256, 0, stream>>>(
        Obuf, Wot, b_out, out, E_, E_);
}